// Round 1
// baseline (578.549 us; speedup 1.0000x reference)
//
#include <hip/hip_runtime.h>
#include <hip/hip_bf16.h>

// Sizes (fixed by the reference)
#define B_N     1024
#define IN_DIM  165
#define EMB_D   150
#define FEAT    315     // IN_DIM + EMB
#define H0_W    325     // FEAT + MB_OUT
#define MB_OUT  10
#define MB_INT  50
#define MROW    64      // padded row stride for M2 (floats)

// ---------------- build x = concat(ts, emb[cond]) into h0[:, 0:315] ------------
__global__ __launch_bounds__(320) void build_x_kernel(
    const float* __restrict__ ts, const int* __restrict__ cond,
    const float* __restrict__ emb, float* __restrict__ h0)
{
    int b = blockIdx.x, t = threadIdx.x;
    if (t < IN_DIM) {
        h0[b * H0_W + t] = ts[b * IN_DIM + t];
    } else if (t < FEAT) {
        int c = cond[b];
        h0[b * H0_W + t] = emb[c * EMB_D + (t - IN_DIM)];
    }
}

// ---------------- generic fp32 tiled GEMM ------------------------------------
// C[M,N] = A[M,K] (lda) * B[K,N] (ldb)  (+bias, leaky-relu)  row-major
// EPI == 0 : C[r*ldc + c] = lrelu(acc + bias[c])
// EPI == 1 : permuted store for M2: o = c/50, k = c%50 ->
//            C[((o*1024) + r)*MROW + k] = acc   (no bias, no act)
#define BM 64
#define BN 64
#define BK 16

template<int EPI>
__global__ __launch_bounds__(256) void gemm_kernel(
    const float* __restrict__ A, const float* __restrict__ Bm,
    const float* __restrict__ bias, float* __restrict__ C,
    int M, int N, int K, int lda, int ldb, int ldc)
{
    __shared__ float As[BK][BM + 4];
    __shared__ float Bs[BK][BN];

    const int t  = threadIdx.x;
    const int bm = blockIdx.y * BM;
    const int bn = blockIdx.x * BN;

    const int tm = (t >> 4) << 2;      // (t/16)*4
    const int tn = (t & 15) << 2;      // (t%16)*4

    const int la_k = t & 15;           // A tile col
    const int la_m = t >> 4;           // A tile row base (step 16)
    const int lb_n = t & 63;           // B tile col
    const int lb_k = t >> 6;           // B tile row base (step 4)

    float acc[4][4] = {};

    for (int k0 = 0; k0 < K; k0 += BK) {
        // stage A tile (rows always valid: M is a multiple of 64 here)
        #pragma unroll
        for (int i = 0; i < 4; ++i) {
            int r = bm + la_m + i * 16;
            int c = k0 + la_k;
            float v = (c < K) ? A[r * lda + c] : 0.f;
            As[la_k][la_m + i * 16] = v;
        }
        // stage B tile
        #pragma unroll
        for (int i = 0; i < 4; ++i) {
            int kk = lb_k + i * 4;
            int c  = bn + lb_n;
            float v = (k0 + kk < K && c < N) ? Bm[(k0 + kk) * ldb + c] : 0.f;
            Bs[kk][lb_n] = v;
        }
        __syncthreads();

        #pragma unroll
        for (int kk = 0; kk < BK; ++kk) {
            float a0 = As[kk][tm + 0], a1 = As[kk][tm + 1];
            float a2 = As[kk][tm + 2], a3 = As[kk][tm + 3];
            float v0 = Bs[kk][tn + 0], v1 = Bs[kk][tn + 1];
            float v2 = Bs[kk][tn + 2], v3 = Bs[kk][tn + 3];
            acc[0][0] += a0 * v0; acc[0][1] += a0 * v1; acc[0][2] += a0 * v2; acc[0][3] += a0 * v3;
            acc[1][0] += a1 * v0; acc[1][1] += a1 * v1; acc[1][2] += a1 * v2; acc[1][3] += a1 * v3;
            acc[2][0] += a2 * v0; acc[2][1] += a2 * v1; acc[2][2] += a2 * v2; acc[2][3] += a2 * v3;
            acc[3][0] += a3 * v0; acc[3][1] += a3 * v1; acc[3][2] += a3 * v2; acc[3][3] += a3 * v3;
        }
        __syncthreads();
    }

    #pragma unroll
    for (int i = 0; i < 4; ++i) {
        int r = bm + tm + i;
        #pragma unroll
        for (int j = 0; j < 4; ++j) {
            int c = bn + tn + j;
            if (c < N) {
                if (EPI == 0) {
                    float v = acc[i][j] + bias[c];
                    v = (v > 0.f) ? v : 0.2f * v;
                    C[r * ldc + c] = v;
                } else {
                    int o = c / MB_INT;
                    int k = c - o * MB_INT;
                    C[(o * B_N + r) * MROW + k] = acc[i][j];
                }
            }
        }
    }
}

// ---------------- pairwise L1 + exp (minibatch discrimination) ----------------
// M2 layout: [o][b][MROW], row stride MROW=64 floats (256 B aligned)
// grid = (16 b-tiles, 10 o, 16 b2-chunks of 64), block = 1 wave (64 lanes)
// part layout: [ch][o][b]
__global__ __launch_bounds__(64) void pairwise_kernel(
    const float* __restrict__ M2, float* __restrict__ part)
{
    const int btile = blockIdx.x;
    const int o     = blockIdx.y;
    const int ch    = blockIdx.z;
    const int lane  = threadIdx.x;
    const int b     = btile * 64 + lane;

    // own row into registers (256B-aligned, float4 loads)
    float m[52];
    const float4* mr = (const float4*)(M2 + (o * B_N + b) * MROW);
    #pragma unroll
    for (int j = 0; j < 13; ++j) {
        float4 v = mr[j];
        m[j * 4 + 0] = v.x; m[j * 4 + 1] = v.y; m[j * 4 + 2] = v.z; m[j * 4 + 3] = v.w;
    }

    float acc = 0.f;
    const float* p = M2 + (o * B_N + ch * 64) * MROW;
    for (int b2 = 0; b2 < 64; ++b2) {
        const float4* q = (const float4*)(p + b2 * MROW);   // wave-uniform address
        float s0 = 0.f, s1 = 0.f, s2 = 0.f, s3 = 0.f;
        #pragma unroll
        for (int j4 = 0; j4 < 12; ++j4) {
            float4 v = q[j4];
            s0 += fabsf(m[j4 * 4 + 0] - v.x);
            s1 += fabsf(m[j4 * 4 + 1] - v.y);
            s2 += fabsf(m[j4 * 4 + 2] - v.z);
            s3 += fabsf(m[j4 * 4 + 3] - v.w);
        }
        float2 v2 = *(const float2*)(p + b2 * MROW + 48);
        s0 += fabsf(m[48] - v2.x);
        s1 += fabsf(m[49] - v2.y);
        float s = (s0 + s1) + (s2 + s3);
        acc += __expf(-s);
    }
    part[(ch * MB_OUT + o) * B_N + b] = acc;
}

// ---------------- reduce partials into h0[:, 315:325] -------------------------
__global__ __launch_bounds__(256) void mb_reduce_kernel(
    const float* __restrict__ part, float* __restrict__ h0)
{
    int i = blockIdx.x * 256 + threadIdx.x;   // i < 10240
    if (i < MB_OUT * B_N) {
        int o = i / B_N, b = i - o * B_N;
        float s = 0.f;
        #pragma unroll
        for (int ch = 0; ch < 16; ++ch)
            s += part[(ch * MB_OUT + o) * B_N + b];
        h0[b * H0_W + FEAT + o] = s;
    }
}

// ---------------- final layer: sigmoid(h4 @ W5 + b5) --------------------------
// one wave per row; K = 256 -> each lane takes a float4
__global__ __launch_bounds__(256) void final_kernel(
    const float* __restrict__ h4, const float* __restrict__ W5,
    const float* __restrict__ b5, float* __restrict__ out)
{
    const int wave = threadIdx.x >> 6;
    const int lane = threadIdx.x & 63;
    const int row  = blockIdx.x * 4 + wave;

    const float4 h = ((const float4*)(h4 + row * 256))[lane];
    const float4 w = ((const float4*)W5)[lane];
    float s = h.x * w.x + h.y * w.y + h.z * w.z + h.w * w.w;
    #pragma unroll
    for (int off = 32; off > 0; off >>= 1)
        s += __shfl_xor(s, off);
    if (lane == 0) {
        float z = s + b5[0];
        out[row] = 1.f / (1.f + __expf(-z));
    }
}

// ---------------- launch ------------------------------------------------------
extern "C" void kernel_launch(void* const* d_in, const int* in_sizes, int n_in,
                              void* d_out, int out_size, void* d_ws, size_t ws_size,
                              hipStream_t stream)
{
    const float* ts   = (const float*)d_in[0];
    const int*   cond = (const int*)  d_in[1];
    const float* emb  = (const float*)d_in[2];
    const float* T    = (const float*)d_in[3];
    const float* W1   = (const float*)d_in[4];
    const float* b1   = (const float*)d_in[5];
    const float* W2   = (const float*)d_in[6];
    const float* b2   = (const float*)d_in[7];
    const float* W3   = (const float*)d_in[8];
    const float* b3   = (const float*)d_in[9];
    const float* W4   = (const float*)d_in[10];
    const float* b4   = (const float*)d_in[11];
    const float* W5   = (const float*)d_in[12];
    const float* b5   = (const float*)d_in[13];
    float* out = (float*)d_out;

    // workspace layout (floats), with liveness-based aliasing
    float* h0   = (float*)d_ws;            // 1024*325   = 332800
    float* M2   = h0   + 332800;           // 10*1024*64 = 655360
    float* part = M2   + 655360;           // 16*10*1024 = 163840
    float* h1   = part + 163840;           // 1024*1536  = 1572864
    float* h2   = h1   + 1572864;          // 1024*1024  = 1048576
    float* h3   = M2;                      // alias: M2 dead after pairwise
    float* h4   = h1;                      // alias: h1 dead after G2
    // total distinct: 3,773,440 floats = ~15.1 MB

    build_x_kernel<<<B_N, 320, 0, stream>>>(ts, cond, emb, h0);

    // M = x @ T  (1024 x 500, K=315), permuted store into M2
    {
        dim3 g((500 + BN - 1) / BN, B_N / BM);
        gemm_kernel<1><<<g, 256, 0, stream>>>(h0, T, nullptr, M2,
                                              B_N, 500, FEAT, H0_W, 500, 0);
    }

    {
        dim3 g(B_N / 64, MB_OUT, 16);
        pairwise_kernel<<<g, 64, 0, stream>>>(M2, part);
    }
    mb_reduce_kernel<<<(MB_OUT * B_N + 255) / 256, 256, 0, stream>>>(part, h0);

    {
        dim3 g(1536 / BN, B_N / BM);
        gemm_kernel<0><<<g, 256, 0, stream>>>(h0, W1, b1, h1,
                                              B_N, 1536, H0_W, H0_W, 1536, 1536);
    }
    {
        dim3 g(1024 / BN, B_N / BM);
        gemm_kernel<0><<<g, 256, 0, stream>>>(h1, W2, b2, h2,
                                              B_N, 1024, 1536, 1536, 1024, 1024);
    }
    {
        dim3 g(512 / BN, B_N / BM);
        gemm_kernel<0><<<g, 256, 0, stream>>>(h2, W3, b3, h3,
                                              B_N, 512, 1024, 1024, 512, 512);
    }
    {
        dim3 g(256 / BN, B_N / BM);
        gemm_kernel<0><<<g, 256, 0, stream>>>(h3, W4, b4, h4,
                                              B_N, 256, 512, 512, 256, 256);
    }
    final_kernel<<<B_N / 4, 256, 0, stream>>>(h4, W5, b5, out);
}

// Round 2
// 175.542 us; speedup vs baseline: 3.2958x; 3.2958x over previous
//
#include <hip/hip_runtime.h>
#include <hip/hip_bf16.h>

#define B_N     1024
#define IN_DIM  165
#define EMB_D   150
#define FEAT    315
#define H0_W    325
#define MB_OUT  10
#define MB_INT  50
#define MROW    64

typedef __attribute__((ext_vector_type(8))) short short8;
typedef __attribute__((ext_vector_type(4))) float f32x4;

// round-to-nearest-even fp32 -> bf16 bits
__device__ __forceinline__ ushort f2bf(float f) {
    uint u = __float_as_uint(f);
    return (ushort)((u + 0x7fffu + ((u >> 16) & 1u)) >> 16);
}
__device__ __forceinline__ uint pack_split(float v) {
    ushort h = f2bf(v);
    float hf = __uint_as_float((uint)h << 16);
    ushort l = f2bf(v - hf);
    return (uint)h | ((uint)l << 16);
}
__device__ __forceinline__ float unpack_split(uint u) {
    return __uint_as_float(u << 16) + __uint_as_float(u & 0xffff0000u);
}

// ---------------- build x = concat(ts, emb[cond]) packed -----------------------
__global__ __launch_bounds__(320) void build_x_kernel(
    const float* __restrict__ ts, const int* __restrict__ cond,
    const float* __restrict__ emb, uint* __restrict__ h0p)
{
    int b = blockIdx.x, t = threadIdx.x;
    float v;
    if (t < IN_DIM)      v = ts[b * IN_DIM + t];
    else if (t < FEAT)   v = emb[cond[b] * EMB_D + (t - IN_DIM)];
    else return;
    h0p[b * H0_W + t] = pack_split(v);
}

// ---------------- MFMA bf16-split GEMM -----------------------------------------
// A: packed u32 (hi|lo<<16) [1024 x K] lda ; B: fp32 [K x N] ldb
// EPI 0: Cout = packed u32, lrelu(acc+bias)
// EPI 1: Cout = fp32 M2 permuted: col -> (o=col/50, k=col%50), [(o*1024+r)*64+k]
// FAST: K%32==0, N%64==0, lda%4==0 (no guards, vector A loads)
template<int EPI, bool FAST>
__global__ __launch_bounds__(256) void gemm_mfma(
    const uint*  __restrict__ Ap, const float* __restrict__ Bw,
    const float* __restrict__ bias, void* __restrict__ Cout,
    int N, int K, int lda, int ldb, int ldc)
{
    __shared__ ushort Ah[64 * 32], Al[64 * 32], Bh[64 * 32], Bl[64 * 32];

    const int t    = threadIdx.x;
    const int bm   = blockIdx.y << 6;
    const int bn   = blockIdx.x << 6;
    const int wid  = t >> 6, lane = t & 63;
    const int wm   = (wid >> 1) << 5, wn = (wid & 1) << 5;
    const int lm   = lane & 15, lc = lane >> 4;

    const int ar  = t >> 2, ac = t & 3;     // A staging: row, k-chunk
    const int bn2 = t & 63, bk = t >> 6;    // B staging: col, k-chunk

    const int kIter = (K + 31) >> 5;

    // LDS write offsets (chunk-XOR swizzle on 16B chunks)
    const int aw = ar  * 32 + ((ac ^ (ar  & 3)) << 3);
    const int bw = bn2 * 32 + ((bk ^ (bn2 & 3)) << 3);
    // fragment read offsets
    const int sw = (lc ^ (lm & 3)) << 3;
    const int a0 = (wm + lm)      * 32 + sw;
    const int a1 = (wm + 16 + lm) * 32 + sw;
    const int b0 = (wn + lm)      * 32 + sw;
    const int b1 = (wn + 16 + lm) * 32 + sw;

    uint  curA[8], nxtA[8];
    float curB[8], nxtB[8];

    auto loadA = [&](int k0, uint* dst) {
        const uint* p = Ap + (bm + ar) * lda + k0 + (ac << 3);
        if (FAST) {
            uint4 v0 = *(const uint4*)p;
            uint4 v1 = *(const uint4*)(p + 4);
            dst[0] = v0.x; dst[1] = v0.y; dst[2] = v0.z; dst[3] = v0.w;
            dst[4] = v1.x; dst[5] = v1.y; dst[6] = v1.z; dst[7] = v1.w;
        } else {
            int kb = k0 + (ac << 3);
            #pragma unroll
            for (int j = 0; j < 8; ++j)
                dst[j] = (kb + j < K) ? p[j] : 0u;
        }
    };
    auto loadB = [&](int k0, float* dst) {
        int kb = k0 + (bk << 3);
        const float* p = Bw + kb * ldb + bn + bn2;
        if (FAST) {
            #pragma unroll
            for (int j = 0; j < 8; ++j) dst[j] = p[j * ldb];
        } else {
            bool cok = (bn + bn2) < N;
            #pragma unroll
            for (int j = 0; j < 8; ++j)
                dst[j] = (cok && (kb + j) < K) ? p[j * ldb] : 0.f;
        }
    };

    f32x4 acc[2][2] = {};

    loadA(0, curA);
    loadB(0, curB);

    for (int it = 0; it < kIter; ++it) {
        // split/extract current tile
        short8 vah, val, vbh, vbl;
        #pragma unroll
        for (int j = 0; j < 8; ++j) {
            vah[j] = (short)(curA[j] & 0xffffu);
            val[j] = (short)(curA[j] >> 16);
            float v = curB[j];
            ushort h = f2bf(v);
            float hf = __uint_as_float((uint)h << 16);
            vbh[j] = (short)h;
            vbl[j] = (short)f2bf(v - hf);
        }
        __syncthreads();                       // prev iter's LDS readers done
        *(short8*)&Ah[aw] = vah;
        *(short8*)&Al[aw] = val;
        *(short8*)&Bh[bw] = vbh;
        *(short8*)&Bl[bw] = vbl;
        __syncthreads();                       // tile visible

        if (it + 1 < kIter) {                  // prefetch next K-tile into regs;
            loadA((it + 1) << 5, nxtA);        // latency hides under frag+MFMA
            loadB((it + 1) << 5, nxtB);
        }

        short8 fah0 = *(const short8*)&Ah[a0];
        short8 fah1 = *(const short8*)&Ah[a1];
        short8 fal0 = *(const short8*)&Al[a0];
        short8 fal1 = *(const short8*)&Al[a1];
        short8 fbh0 = *(const short8*)&Bh[b0];
        short8 fbh1 = *(const short8*)&Bh[b1];
        short8 fbl0 = *(const short8*)&Bl[b0];
        short8 fbl1 = *(const short8*)&Bl[b1];

        acc[0][0] = __builtin_amdgcn_mfma_f32_16x16x32_bf16(fah0, fbh0, acc[0][0], 0, 0, 0);
        acc[0][1] = __builtin_amdgcn_mfma_f32_16x16x32_bf16(fah0, fbh1, acc[0][1], 0, 0, 0);
        acc[1][0] = __builtin_amdgcn_mfma_f32_16x16x32_bf16(fah1, fbh0, acc[1][0], 0, 0, 0);
        acc[1][1] = __builtin_amdgcn_mfma_f32_16x16x32_bf16(fah1, fbh1, acc[1][1], 0, 0, 0);
        acc[0][0] = __builtin_amdgcn_mfma_f32_16x16x32_bf16(fah0, fbl0, acc[0][0], 0, 0, 0);
        acc[0][1] = __builtin_amdgcn_mfma_f32_16x16x32_bf16(fah0, fbl1, acc[0][1], 0, 0, 0);
        acc[1][0] = __builtin_amdgcn_mfma_f32_16x16x32_bf16(fah1, fbl0, acc[1][0], 0, 0, 0);
        acc[1][1] = __builtin_amdgcn_mfma_f32_16x16x32_bf16(fah1, fbl1, acc[1][1], 0, 0, 0);
        acc[0][0] = __builtin_amdgcn_mfma_f32_16x16x32_bf16(fal0, fbh0, acc[0][0], 0, 0, 0);
        acc[0][1] = __builtin_amdgcn_mfma_f32_16x16x32_bf16(fal0, fbh1, acc[0][1], 0, 0, 0);
        acc[1][0] = __builtin_amdgcn_mfma_f32_16x16x32_bf16(fal1, fbh0, acc[1][0], 0, 0, 0);
        acc[1][1] = __builtin_amdgcn_mfma_f32_16x16x32_bf16(fal1, fbh1, acc[1][1], 0, 0, 0);

        #pragma unroll
        for (int j = 0; j < 8; ++j) { curA[j] = nxtA[j]; curB[j] = nxtB[j]; }
    }

    // epilogue: C/D frag layout row=(lane>>4)*4+r, col=lane&15
    #pragma unroll
    for (int mi = 0; mi < 2; ++mi)
    #pragma unroll
    for (int ni = 0; ni < 2; ++ni) {
        #pragma unroll
        for (int r = 0; r < 4; ++r) {
            int row = bm + wm + mi * 16 + lc * 4 + r;
            int col = bn + wn + ni * 16 + lm;
            float v = acc[mi][ni][r];
            if (EPI == 0) {
                v += bias[col];
                v = (v > 0.f) ? v : 0.2f * v;
                ((uint*)Cout)[row * ldc + col] = pack_split(v);
            } else {
                if (col < N) {
                    int o = col / MB_INT, kk = col - o * MB_INT;
                    ((float*)Cout)[(o * B_N + row) * MROW + kk] = v;
                }
            }
        }
    }
}

// ---------------- pairwise L1 + exp --------------------------------------------
// grid (4, 10, 16): 4 btile-groups x o x ch ; block 256 (4 waves, 1 btile each)
__global__ __launch_bounds__(256) void pairwise_kernel(
    const float* __restrict__ M2, float* __restrict__ part)
{
    __shared__ float Ls[64][64];
    const int grp = blockIdx.x, o = blockIdx.y, ch = blockIdx.z;
    const int t = threadIdx.x, wid = t >> 6, lane = t & 63;

    // stage the 64-row b2 chunk (incl pad cols; only 0..49 consumed)
    {
        const float4* src = (const float4*)(M2 + (o * B_N + ch * 64) * MROW);
        #pragma unroll
        for (int s = 0; s < 4; ++s) {
            int idx = t + s * 256;               // 0..1023 = 64 rows x 16 float4
            ((float4*)Ls)[idx] = src[idx];
        }
    }
    __syncthreads();

    const int b = (grp * 4 + wid) * 64 + lane;

    float m[52];
    const float4* mr = (const float4*)(M2 + (o * B_N + b) * MROW);
    #pragma unroll
    for (int j = 0; j < 13; ++j) {
        float4 v = mr[j];
        m[j*4+0] = v.x; m[j*4+1] = v.y; m[j*4+2] = v.z; m[j*4+3] = v.w;
    }

    float acc = 0.f;
    for (int b2 = 0; b2 < 64; ++b2) {
        const float4* q = (const float4*)&Ls[b2][0];   // uniform -> broadcast
        float s0 = 0.f, s1 = 0.f, s2 = 0.f, s3 = 0.f;
        #pragma unroll
        for (int j4 = 0; j4 < 12; ++j4) {
            float4 v = q[j4];
            s0 += fabsf(m[j4*4+0] - v.x);
            s1 += fabsf(m[j4*4+1] - v.y);
            s2 += fabsf(m[j4*4+2] - v.z);
            s3 += fabsf(m[j4*4+3] - v.w);
        }
        float4 vt = q[12];
        s0 += fabsf(m[48] - vt.x);
        s1 += fabsf(m[49] - vt.y);
        float s = (s0 + s1) + (s2 + s3);
        acc += __expf(-s);
    }
    part[(ch * MB_OUT + o) * B_N + b] = acc;
}

// ---------------- reduce partials into h0p[:, 315:325] -------------------------
__global__ __launch_bounds__(256) void mb_reduce_kernel(
    const float* __restrict__ part, uint* __restrict__ h0p)
{
    int i = blockIdx.x * 256 + threadIdx.x;
    if (i < MB_OUT * B_N) {
        int o = i / B_N, b = i - o * B_N;
        float s = 0.f;
        #pragma unroll
        for (int ch = 0; ch < 16; ++ch)
            s += part[(ch * MB_OUT + o) * B_N + b];
        h0p[b * H0_W + FEAT + o] = pack_split(s);
    }
}

// ---------------- final layer: sigmoid(h4 @ W5 + b5) ---------------------------
__global__ __launch_bounds__(256) void final_kernel(
    const uint* __restrict__ h4p, const float* __restrict__ W5,
    const float* __restrict__ b5, float* __restrict__ out)
{
    const int wave = threadIdx.x >> 6;
    const int lane = threadIdx.x & 63;
    const int row  = blockIdx.x * 4 + wave;

    const uint4  h = ((const uint4*)(h4p + row * 256))[lane];
    const float4 w = ((const float4*)W5)[lane];
    float s = unpack_split(h.x) * w.x + unpack_split(h.y) * w.y
            + unpack_split(h.z) * w.z + unpack_split(h.w) * w.w;
    #pragma unroll
    for (int off = 32; off > 0; off >>= 1)
        s += __shfl_xor(s, off);
    if (lane == 0) {
        float z = s + b5[0];
        out[row] = 1.f / (1.f + __expf(-z));
    }
}

// ---------------- launch -------------------------------------------------------
extern "C" void kernel_launch(void* const* d_in, const int* in_sizes, int n_in,
                              void* d_out, int out_size, void* d_ws, size_t ws_size,
                              hipStream_t stream)
{
    const float* ts   = (const float*)d_in[0];
    const int*   cond = (const int*)  d_in[1];
    const float* emb  = (const float*)d_in[2];
    const float* T    = (const float*)d_in[3];
    const float* W1   = (const float*)d_in[4];
    const float* b1   = (const float*)d_in[5];
    const float* W2   = (const float*)d_in[6];
    const float* b2   = (const float*)d_in[7];
    const float* W3   = (const float*)d_in[8];
    const float* b3   = (const float*)d_in[9];
    const float* W4   = (const float*)d_in[10];
    const float* b4   = (const float*)d_in[11];
    const float* W5   = (const float*)d_in[12];
    const float* b5   = (const float*)d_in[13];
    float* out = (float*)d_out;

    // workspace (4-byte units)
    uint*  h0p  = (uint*)d_ws;             // 1024*325   = 332800
    float* M2   = (float*)(h0p + 332800);  // 10*1024*64 = 655360
    float* part = M2 + 655360;             // 16*10*1024 = 163840
    uint*  h1p  = (uint*)(part + 163840);  // 1024*1536
    uint*  h2p  = h1p + 1572864;           // 1024*1024
    uint*  h3p  = (uint*)M2;               // alias: M2 dead after pairwise (524288 <= 655360)
    uint*  h4p  = h1p;                     // alias: h1 dead after W2 gemm

    build_x_kernel<<<B_N, 320, 0, stream>>>(ts, cond, emb, h0p);

    { dim3 g(8, 16);  gemm_mfma<1,false><<<g, 256, 0, stream>>>(h0p, T,  nullptr, M2,  500, FEAT, H0_W, 500, 0); }
    { dim3 g(4, MB_OUT, 16); pairwise_kernel<<<g, 256, 0, stream>>>(M2, part); }
    mb_reduce_kernel<<<(MB_OUT * B_N + 255) / 256, 256, 0, stream>>>(part, h0p);

    { dim3 g(24, 16); gemm_mfma<0,false><<<g, 256, 0, stream>>>(h0p, W1, b1, h1p, 1536, H0_W, H0_W, 1536, 1536); }
    { dim3 g(16, 16); gemm_mfma<0,true ><<<g, 256, 0, stream>>>(h1p, W2, b2, h2p, 1024, 1536, 1536, 1024, 1024); }
    { dim3 g(8, 16);  gemm_mfma<0,true ><<<g, 256, 0, stream>>>(h2p, W3, b3, h3p,  512, 1024, 1024,  512,  512); }
    { dim3 g(4, 16);  gemm_mfma<0,true ><<<g, 256, 0, stream>>>(h3p, W4, b4, h4p,  256,  512,  512,  256,  256); }

    final_kernel<<<B_N / 4, 256, 0, stream>>>(h4p, W5, b5, out);
}

// Round 3
// 161.736 us; speedup vs baseline: 3.5771x; 1.0854x over previous
//
#include <hip/hip_runtime.h>
#include <hip/hip_bf16.h>

#define B_N     1024
#define IN_DIM  165
#define EMB_D   150
#define FEAT    315
#define H0_W    325
#define MB_OUT  10
#define MB_INT  50
#define MROW    64

typedef __attribute__((ext_vector_type(8))) short short8;
typedef __attribute__((ext_vector_type(4))) float f32x4;

__device__ __forceinline__ ushort f2bf(float f) {
    uint u = __float_as_uint(f);
    return (ushort)((u + 0x7fffu + ((u >> 16) & 1u)) >> 16);
}
__device__ __forceinline__ uint pack_split(float v) {
    ushort h = f2bf(v);
    float hf = __uint_as_float((uint)h << 16);
    ushort l = f2bf(v - hf);
    return (uint)h | ((uint)l << 16);
}
__device__ __forceinline__ float unpack_split(uint u) {
    return __uint_as_float(u << 16) + __uint_as_float(u & 0xffff0000u);
}

// ---------------- build x = concat(ts, emb[cond]) packed -----------------------
__global__ __launch_bounds__(320) void build_x_kernel(
    const float* __restrict__ ts, const int* __restrict__ cond,
    const float* __restrict__ emb, uint* __restrict__ h0p)
{
    int b = blockIdx.x, t = threadIdx.x;
    float v;
    if (t < IN_DIM)      v = ts[b * IN_DIM + t];
    else if (t < FEAT)   v = emb[cond[b] * EMB_D + (t - IN_DIM)];
    else return;
    h0p[b * H0_W + t] = pack_split(v);
}

// ---------------- MFMA bf16-split GEMM with optional K-split -------------------
// A: packed u32 [1024 x K] lda ; B: fp32 [K x N] ldb
// gridDim.z > 1 : store fp32 partial to Pout + z*B_N*N  (row*N+col)
// else EPI 0: packed u32 lrelu(acc+bias) ; EPI 1: fp32 M2-permuted store
template<int EPI, bool FAST>
__global__ __launch_bounds__(256) void gemm_mfma(
    const uint*  __restrict__ Ap, const float* __restrict__ Bw,
    const float* __restrict__ bias, void* __restrict__ Cout,
    int N, int K, int lda, int ldb, int ldc,
    int kIterTotal, int Ks, float* __restrict__ Pout)
{
    __shared__ ushort Ah[64 * 32], Al[64 * 32], Bh[64 * 32], Bl[64 * 32];

    const int t    = threadIdx.x;
    const int bm   = blockIdx.y << 6;
    const int bn   = blockIdx.x << 6;
    const int wid  = t >> 6, lane = t & 63;
    const int wm   = (wid >> 1) << 5, wn = (wid & 1) << 5;
    const int lm   = lane & 15, lc = lane >> 4;

    const int ar  = t >> 2, ac = t & 3;
    const int bn2 = t & 63, bk = t >> 6;

    const int z   = blockIdx.z;
    const int it0 = z * Ks;
    const int nIt = min(Ks, kIterTotal - it0);

    const int aw = ar  * 32 + ((ac ^ (ar  & 3)) << 3);
    const int bw = bn2 * 32 + ((bk ^ (bn2 & 3)) << 3);
    const int sw = (lc ^ (lm & 3)) << 3;
    const int a0 = (wm + lm)      * 32 + sw;
    const int a1 = (wm + 16 + lm) * 32 + sw;
    const int b0 = (wn + lm)      * 32 + sw;
    const int b1 = (wn + 16 + lm) * 32 + sw;

    uint  curA[8], nxtA[8];
    float curB[8], nxtB[8];

    auto loadA = [&](int k0, uint* dst) {
        const uint* p = Ap + (bm + ar) * lda + k0 + (ac << 3);
        if (FAST) {
            uint4 v0 = *(const uint4*)p;
            uint4 v1 = *(const uint4*)(p + 4);
            dst[0] = v0.x; dst[1] = v0.y; dst[2] = v0.z; dst[3] = v0.w;
            dst[4] = v1.x; dst[5] = v1.y; dst[6] = v1.z; dst[7] = v1.w;
        } else {
            int kb = k0 + (ac << 3);
            #pragma unroll
            for (int j = 0; j < 8; ++j)
                dst[j] = (kb + j < K) ? p[j] : 0u;
        }
    };
    auto loadB = [&](int k0, float* dst) {
        int kb = k0 + (bk << 3);
        const float* p = Bw + kb * ldb + bn + bn2;
        if (FAST) {
            #pragma unroll
            for (int j = 0; j < 8; ++j) dst[j] = p[j * ldb];
        } else {
            bool cok = (bn + bn2) < N;
            #pragma unroll
            for (int j = 0; j < 8; ++j)
                dst[j] = (cok && (kb + j) < K) ? p[j * ldb] : 0.f;
        }
    };

    f32x4 acc[2][2] = {};

    loadA(it0 << 5, curA);
    loadB(it0 << 5, curB);

    for (int it = 0; it < nIt; ++it) {
        short8 vah, val, vbh, vbl;
        #pragma unroll
        for (int j = 0; j < 8; ++j) {
            vah[j] = (short)(curA[j] & 0xffffu);
            val[j] = (short)(curA[j] >> 16);
            float v = curB[j];
            ushort h = f2bf(v);
            float hf = __uint_as_float((uint)h << 16);
            vbh[j] = (short)h;
            vbl[j] = (short)f2bf(v - hf);
        }
        __syncthreads();
        *(short8*)&Ah[aw] = vah;
        *(short8*)&Al[aw] = val;
        *(short8*)&Bh[bw] = vbh;
        *(short8*)&Bl[bw] = vbl;
        __syncthreads();

        if (it + 1 < nIt) {
            loadA((it0 + it + 1) << 5, nxtA);
            loadB((it0 + it + 1) << 5, nxtB);
        }

        short8 fah0 = *(const short8*)&Ah[a0];
        short8 fah1 = *(const short8*)&Ah[a1];
        short8 fal0 = *(const short8*)&Al[a0];
        short8 fal1 = *(const short8*)&Al[a1];
        short8 fbh0 = *(const short8*)&Bh[b0];
        short8 fbh1 = *(const short8*)&Bh[b1];
        short8 fbl0 = *(const short8*)&Bl[b0];
        short8 fbl1 = *(const short8*)&Bl[b1];

        acc[0][0] = __builtin_amdgcn_mfma_f32_16x16x32_bf16(fah0, fbh0, acc[0][0], 0, 0, 0);
        acc[0][1] = __builtin_amdgcn_mfma_f32_16x16x32_bf16(fah0, fbh1, acc[0][1], 0, 0, 0);
        acc[1][0] = __builtin_amdgcn_mfma_f32_16x16x32_bf16(fah1, fbh0, acc[1][0], 0, 0, 0);
        acc[1][1] = __builtin_amdgcn_mfma_f32_16x16x32_bf16(fah1, fbh1, acc[1][1], 0, 0, 0);
        acc[0][0] = __builtin_amdgcn_mfma_f32_16x16x32_bf16(fah0, fbl0, acc[0][0], 0, 0, 0);
        acc[0][1] = __builtin_amdgcn_mfma_f32_16x16x32_bf16(fah0, fbl1, acc[0][1], 0, 0, 0);
        acc[1][0] = __builtin_amdgcn_mfma_f32_16x16x32_bf16(fah1, fbl0, acc[1][0], 0, 0, 0);
        acc[1][1] = __builtin_amdgcn_mfma_f32_16x16x32_bf16(fah1, fbl1, acc[1][1], 0, 0, 0);
        acc[0][0] = __builtin_amdgcn_mfma_f32_16x16x32_bf16(fal0, fbh0, acc[0][0], 0, 0, 0);
        acc[0][1] = __builtin_amdgcn_mfma_f32_16x16x32_bf16(fal0, fbh1, acc[0][1], 0, 0, 0);
        acc[1][0] = __builtin_amdgcn_mfma_f32_16x16x32_bf16(fal1, fbh0, acc[1][0], 0, 0, 0);
        acc[1][1] = __builtin_amdgcn_mfma_f32_16x16x32_bf16(fal1, fbh1, acc[1][1], 0, 0, 0);

        #pragma unroll
        for (int j = 0; j < 8; ++j) { curA[j] = nxtA[j]; curB[j] = nxtB[j]; }
    }

    if (gridDim.z > 1) {
        float* P = Pout + (size_t)z * B_N * N;
        #pragma unroll
        for (int mi = 0; mi < 2; ++mi)
        #pragma unroll
        for (int ni = 0; ni < 2; ++ni)
        #pragma unroll
        for (int r = 0; r < 4; ++r) {
            int row = bm + wm + mi * 16 + lc * 4 + r;
            int col = bn + wn + ni * 16 + lm;
            if (col < N) P[row * N + col] = acc[mi][ni][r];
        }
        return;
    }

    #pragma unroll
    for (int mi = 0; mi < 2; ++mi)
    #pragma unroll
    for (int ni = 0; ni < 2; ++ni)
    #pragma unroll
    for (int r = 0; r < 4; ++r) {
        int row = bm + wm + mi * 16 + lc * 4 + r;
        int col = bn + wn + ni * 16 + lm;
        float v = acc[mi][ni][r];
        if (EPI == 0) {
            v += bias[col];
            v = (v > 0.f) ? v : 0.2f * v;
            ((uint*)Cout)[row * ldc + col] = pack_split(v);
        } else {
            if (col < N) {
                int o = col / MB_INT, kk = col - o * MB_INT;
                ((float*)Cout)[(o * B_N + row) * MROW + kk] = v;
            }
        }
    }
}

// ---------------- split-K epilogues -------------------------------------------
// sum S partials (fixed order), bias + lrelu + pack -> u32 activations
__global__ __launch_bounds__(256) void epi_pack_kernel(
    const float* __restrict__ P, const float* __restrict__ bias,
    uint* __restrict__ outp, int n4, int S)
{
    const int c4 = blockIdx.x * 64 + (threadIdx.x & 63);
    const int r  = blockIdx.y * 4 + (threadIdx.x >> 6);
    const int idx = r * n4 + c4;
    const float4* P4 = (const float4*)P;
    float4 v = P4[idx];
    for (int s = 1; s < S; ++s) {
        float4 w = P4[(size_t)s * B_N * n4 + idx];
        v.x += w.x; v.y += w.y; v.z += w.z; v.w += w.w;
    }
    float4 bb = ((const float4*)bias)[c4];
    v.x += bb.x; v.y += bb.y; v.z += bb.z; v.w += bb.w;
    v.x = (v.x > 0.f) ? v.x : 0.2f * v.x;
    v.y = (v.y > 0.f) ? v.y : 0.2f * v.y;
    v.z = (v.z > 0.f) ? v.z : 0.2f * v.z;
    v.w = (v.w > 0.f) ? v.w : 0.2f * v.w;
    uint4 o;
    o.x = pack_split(v.x); o.y = pack_split(v.y);
    o.z = pack_split(v.z); o.w = pack_split(v.w);
    ((uint4*)outp)[idx] = o;
}

// sum S partials of the T-GEMM ([1024][500]) and scatter into M2 layout
__global__ __launch_bounds__(256) void epi_m2_kernel(
    const float* __restrict__ P, float* __restrict__ M2, int S)
{
    int i = blockIdx.x * 256 + threadIdx.x;   // < 1024*500
    if (i >= B_N * 500) return;
    int r = i / 500, c = i - r * 500;
    float v = P[i];
    for (int s = 1; s < S; ++s) v += P[(size_t)s * B_N * 500 + i];
    int o = c / MB_INT, k = c - o * MB_INT;
    M2[(o * B_N + r) * MROW + k] = v;
}

// ---------------- symmetric pairwise L1 + exp ----------------------------------
// grid (4, 10, 16): wave w of block grp handles btile = grp*4+w vs chunk ch.
// Only btile <= ch computed; off-diagonal waves also emit the transposed
// (column) partial via a wave butterfly. part[(src*10+o)*1024 + b].
__global__ __launch_bounds__(256) void pairwise_kernel(
    const float* __restrict__ M2, float* __restrict__ part)
{
    const int grp = blockIdx.x, o = blockIdx.y, ch = blockIdx.z;
    if (grp * 4 > ch) return;                 // block entirely above diagonal
    __shared__ float Ls[64][64];
    const int t = threadIdx.x, wid = t >> 6, lane = t & 63;

    {
        const float4* src = (const float4*)(M2 + (o * B_N + ch * 64) * MROW);
        #pragma unroll
        for (int s = 0; s < 4; ++s)
            ((float4*)Ls)[t + s * 256] = src[t + s * 256];
    }
    __syncthreads();

    const int btile = grp * 4 + wid;
    if (btile > ch) return;                   // inactive wave (after the only sync)
    const bool offd = (btile < ch);
    const int b = btile * 64 + lane;

    float m[52];
    const float4* mr = (const float4*)(M2 + (o * B_N + b) * MROW);
    #pragma unroll
    for (int j = 0; j < 13; ++j) {
        float4 v = mr[j];
        m[j*4+0] = v.x; m[j*4+1] = v.y; m[j*4+2] = v.z; m[j*4+3] = v.w;
    }

    float rowacc = 0.f, colacc = 0.f;
    for (int b2 = 0; b2 < 64; ++b2) {
        const float4* q = (const float4*)&Ls[b2][0];   // uniform -> broadcast
        float s0 = 0.f, s1 = 0.f, s2 = 0.f, s3 = 0.f;
        #pragma unroll
        for (int j4 = 0; j4 < 12; ++j4) {
            float4 v = q[j4];
            s0 += fabsf(m[j4*4+0] - v.x);
            s1 += fabsf(m[j4*4+1] - v.y);
            s2 += fabsf(m[j4*4+2] - v.z);
            s3 += fabsf(m[j4*4+3] - v.w);
        }
        float4 vt = q[12];
        s0 += fabsf(m[48] - vt.x);
        s1 += fabsf(m[49] - vt.y);
        float s = (s0 + s1) + (s2 + s3);
        float e = __expf(-s);
        rowacc += e;
        if (offd) {
            float es = e;
            es += __shfl_xor(es, 1);  es += __shfl_xor(es, 2);
            es += __shfl_xor(es, 4);  es += __shfl_xor(es, 8);
            es += __shfl_xor(es, 16); es += __shfl_xor(es, 32);
            colacc += (lane == b2) ? es : 0.f;
        }
    }
    part[(ch * MB_OUT + o) * B_N + b] = rowacc;
    if (offd) part[(btile * MB_OUT + o) * B_N + ch * 64 + lane] = colacc;
}

// ---------------- reduce partials into h0p[:, 315:325] -------------------------
__global__ __launch_bounds__(256) void mb_reduce_kernel(
    const float* __restrict__ part, uint* __restrict__ h0p)
{
    int i = blockIdx.x * 256 + threadIdx.x;
    if (i < MB_OUT * B_N) {
        int o = i / B_N, b = i - o * B_N;
        float s = 0.f;
        #pragma unroll
        for (int ch = 0; ch < 16; ++ch)
            s += part[(ch * MB_OUT + o) * B_N + b];
        h0p[b * H0_W + FEAT + o] = pack_split(s);
    }
}

// ---------------- final layer: sigmoid(h4 @ W5 + b5) ---------------------------
__global__ __launch_bounds__(256) void final_kernel(
    const uint* __restrict__ h4p, const float* __restrict__ W5,
    const float* __restrict__ b5, float* __restrict__ out)
{
    const int wave = threadIdx.x >> 6;
    const int lane = threadIdx.x & 63;
    const int row  = blockIdx.x * 4 + wave;

    const uint4  h = ((const uint4*)(h4p + row * 256))[lane];
    const float4 w = ((const float4*)W5)[lane];
    float s = unpack_split(h.x) * w.x + unpack_split(h.y) * w.y
            + unpack_split(h.z) * w.z + unpack_split(h.w) * w.w;
    #pragma unroll
    for (int off = 32; off > 0; off >>= 1)
        s += __shfl_xor(s, off);
    if (lane == 0) {
        float z = s + b5[0];
        out[row] = 1.f / (1.f + __expf(-z));
    }
}

// ---------------- launch -------------------------------------------------------
extern "C" void kernel_launch(void* const* d_in, const int* in_sizes, int n_in,
                              void* d_out, int out_size, void* d_ws, size_t ws_size,
                              hipStream_t stream)
{
    const float* ts   = (const float*)d_in[0];
    const int*   cond = (const int*)  d_in[1];
    const float* emb  = (const float*)d_in[2];
    const float* T    = (const float*)d_in[3];
    const float* W1   = (const float*)d_in[4];
    const float* b1   = (const float*)d_in[5];
    const float* W2   = (const float*)d_in[6];
    const float* b2   = (const float*)d_in[7];
    const float* W3   = (const float*)d_in[8];
    const float* b3   = (const float*)d_in[9];
    const float* W4   = (const float*)d_in[10];
    const float* b4   = (const float*)d_in[11];
    const float* W5   = (const float*)d_in[12];
    const float* b5   = (const float*)d_in[13];
    float* out = (float*)d_out;

    // workspace (4-byte units)
    uint*  h0p  = (uint*)d_ws;             // 332800
    float* M2   = (float*)(h0p + 332800);  // 655360
    float* part = M2 + 655360;             // 163840
    uint*  h1p  = (uint*)(part + 163840);  // 1572864
    uint*  h2p  = h1p + 1572864;           // 1048576
    uint*  h3p  = (uint*)M2;               // alias (524288 <= 655360)
    uint*  h4p  = h1p;                     // alias
    const size_t baseU = 3773440;
    size_t capU = (ws_size / 4 > baseU) ? ws_size / 4 - baseU : 0;
    float* Pbuf = (float*)((uint*)d_ws + baseU);

    auto fits = [&](int s, int N) { return (size_t)s * B_N * N <= capU; };
    const int ST = fits(2, 500)  ? 2 : 1;
    const int S1 = fits(2, 1536) ? 2 : 1;
    const int S2 = fits(3, 1024) ? 3 : (fits(2, 1024) ? 2 : 1);
    const int S3 = fits(4, 512)  ? 4 : (fits(2, 512)  ? 2 : 1);
    const int S4 = fits(4, 256)  ? 4 : (fits(2, 256)  ? 2 : 1);

    build_x_kernel<<<B_N, 320, 0, stream>>>(ts, cond, emb, h0p);

    // M = x @ T (K=315, N=500)
    {
        int kit = 10, ks = (kit + ST - 1) / ST;
        dim3 g(8, 16, ST);
        gemm_mfma<1,false><<<g, 256, 0, stream>>>(h0p, T, nullptr, M2,
                                                  500, FEAT, H0_W, 500, 0, kit, ks, Pbuf);
        if (ST > 1)
            epi_m2_kernel<<<(B_N * 500 + 255) / 256, 256, 0, stream>>>(Pbuf, M2, ST);
    }

    { dim3 g(4, MB_OUT, 16); pairwise_kernel<<<g, 256, 0, stream>>>(M2, part); }
    mb_reduce_kernel<<<(MB_OUT * B_N + 255) / 256, 256, 0, stream>>>(part, h0p);

    auto runL = [&](const uint* in, const float* W, const float* bia, uint* outp,
                    int N, int K, int lda, int S, bool fast) {
        int kit = (K + 31) >> 5, ks = (kit + S - 1) / S;
        dim3 g(N / 64, 16, S);
        if (fast) gemm_mfma<0,true ><<<g, 256, 0, stream>>>(in, W, bia, outp, N, K, lda, N, N, kit, ks, Pbuf);
        else      gemm_mfma<0,false><<<g, 256, 0, stream>>>(in, W, bia, outp, N, K, lda, N, N, kit, ks, Pbuf);
        if (S > 1) {
            dim3 ge((N / 4) / 64, B_N / 4);
            epi_pack_kernel<<<ge, 256, 0, stream>>>(Pbuf, bia, outp, N / 4, S);
        }
    };

    runL(h0p, W1, b1, h1p, 1536, H0_W, H0_W, S1, false);
    runL(h1p, W2, b2, h2p, 1024, 1536, 1536, S2, true);
    runL(h2p, W3, b3, h3p,  512, 1024, 1024, S3, true);
    runL(h3p, W4, b4, h4p,  256,  512,  512, S4, true);

    final_kernel<<<B_N / 4, 256, 0, stream>>>(h4p, W5, b5, out);
}